// Round 16
// baseline (654.527 us; speedup 1.0000x reference)
//
#include <hip/hip_runtime.h>
#include <math.h>

#define BB 32
#define NN 1024
#define KK 20
typedef unsigned long long u64;
typedef unsigned int u32;
typedef unsigned short ushort;
static constexpr float EPSF = 1e-5f;

typedef __attribute__((ext_vector_type(8))) short bf16x8;
typedef __attribute__((ext_vector_type(4))) float f32x4;

// ---------------- fused transpose (B,N,3)->(B,3,N) + xx + pooled zero ----------------
__global__ void t3xx_kernel(const float* __restrict__ x, float* __restrict__ xT,
                            float* __restrict__ xx, float* __restrict__ pooled) {
  int t = blockIdx.x * blockDim.x + threadIdx.x;
  if (t >= BB * NN) return;
  if (t < BB * 320) pooled[t] = 0.0f;
  int b = t >> 10, i = t & (NN - 1);
  float v0 = x[(size_t)t * 3 + 0], v1 = x[(size_t)t * 3 + 1], v2 = x[(size_t)t * 3 + 2];
  xT[((size_t)b * 3 + 0) * NN + i] = v0;
  xT[((size_t)b * 3 + 1) * NN + i] = v1;
  xT[((size_t)b * 3 + 2) * NN + i] = v2;
  float s = 0.f;
  s += v0 * v0; s += v1 * v1; s += v2 * v2;
  xx[t] = s;
}

// ---------------- monotone f32 -> u32 order map ----------------
__device__ __forceinline__ u32 map_m(float d) {
  u32 bits = __float_as_uint(d);
  return bits ^ (u32)(((int)bits >> 31) | 0x80000000);
}

__device__ __forceinline__ double shflxd(double v, int m) {
  long long u = __double_as_longlong(v);
  int lo = (int)(u & 0xFFFFFFFFll);
  int hi = (int)(((u64)u) >> 32);
  lo = __shfl_xor(lo, m);
  hi = __shfl_xor(hi, m);
  return __longlong_as_double(((long long)hi << 32) | (u32)lo);
}

// descending bitonic sorts
__device__ __forceinline__ u32 lane_sort64_u32(u32 v, int lane) {
  #pragma unroll
  for (int kk = 2; kk <= 64; kk <<= 1)
    #pragma unroll
    for (int j = kk >> 1; j > 0; j >>= 1) {
      u32 pv = (u32)__shfl_xor((int)v, j);
      bool keepMax = (((lane & j) == 0) == ((lane & kk) == 0));
      u32 mx = v > pv ? v : pv, mn = v > pv ? pv : v;
      v = keepMax ? mx : mn;
    }
  return v;
}

__device__ __forceinline__ double lane_sort64(double v, int lane) {
  #pragma unroll
  for (int kk = 2; kk <= 64; kk <<= 1)
    #pragma unroll
    for (int j = kk >> 1; j > 0; j >>= 1) {
      double pv = shflxd(v, j);
      bool keepMax = (((lane & j) == 0) == ((lane & kk) == 0));
      v = keepMax ? fmax(v, pv) : fmin(v, pv);
    }
  return v;
}

__device__ __forceinline__ double lane_sort32(double v, int lane) {
  #pragma unroll
  for (int kk = 2; kk <= 32; kk <<= 1)
    #pragma unroll
    for (int j = kk >> 1; j > 0; j >>= 1) {
      double pv = shflxd(v, j);
      bool keepMax = (((lane & j) == 0) == ((lane & kk) == 0));
      v = keepMax ? fmax(v, pv) : fmin(v, pv);
    }
  return v;
}

__device__ __forceinline__ void key_decode_write(double res, int lane, int* __restrict__ orow) {
  if (lane < KK) {
    double md = trunc(res * (1.0 / 1024.0));
    double rd = fma(md, -1024.0, res);
    orow[lane] = 1023 - (int)rd;
  }
}

// u32 first-stage filter + f64 survivor sort. m[e], e=(q<<2)|c: j = q*256 + lane*4 + c
__device__ __forceinline__ void topk_sel(u32 (&m)[16], int lane,
                                         volatile double* __restrict__ sb,
                                         int* __restrict__ orow) {
  u32 h = m[0];
  #pragma unroll
  for (int e = 1; e < 16; ++e) h = m[e] > h ? m[e] : h;
  u32 sh = lane_sort64_u32(h, lane);
  u32 T = (u32)__shfl((int)sh, KK - 1);

  int cnt = 0;
  #pragma unroll
  for (int e = 0; e < 16; ++e) cnt += (m[e] >= T) ? 1 : 0;
  int scan = cnt;
  #pragma unroll
  for (int d = 1; d < 64; d <<= 1) {
    int nv = __shfl_up(scan, d);
    if (lane >= d) scan += nv;
  }
  int total = __shfl(scan, 63);
  double based = (double)(1023 - lane * 4);

  if (total <= 64) {
    int ofs = scan - cnt;
    sb[lane] = 0.0;
    #pragma unroll
    for (int e = 0; e < 16; ++e)
      if (m[e] >= T) {
        double kd = fma((double)m[e], 1024.0, based - (double)((e >> 2) * 256 + (e & 3)));
        sb[ofs++] = kd;
      }
    double v = sb[lane];
    v = (total <= 32) ? lane_sort32(v, lane) : lane_sort64(v, lane);
    key_decode_write(v, lane, orow);
  } else {
    // exact fallback (tie-heavy rows): f64-key tournament
    double k[16];
    #pragma unroll
    for (int e = 0; e < 16; ++e)
      k[e] = fma((double)m[e], 1024.0, based - (double)((e >> 2) * 256 + (e & 3)));
    double lm = k[0];
    #pragma unroll
    for (int e = 1; e < 16; ++e) lm = fmax(lm, k[e]);
    double res = 0.0;
    for (int t = 0; t < KK; ++t) {
      double w = lm;
      #pragma unroll
      for (int mm = 1; mm < 64; mm <<= 1) w = fmax(w, shflxd(w, mm));
      if (lane == t) res = w;
      bool win = (lm == w);
      #pragma unroll
      for (int e = 0; e < 16; ++e) k[e] = (k[e] == w) ? 0.0 : k[e];
      if (win) {
        double n0 = fmax(k[0], k[1]);
        #pragma unroll
        for (int e = 2; e < 16; ++e) n0 = fmax(n0, k[e]);
        lm = n0;
      }
    }
    key_decode_write(res, lane, orow);
  }
}

// ---------------- merged: MFMA dist (u32-m output, XCD-swizzled) + uc GEMM ----------------
// dist: operand-swapped MFMA -> uint4 stores. uc: Ws in LDS, A via wave-uniform global reads.
#define CC 64
template<int O>
__global__ __launch_bounds__(256) void ducp_kernel(
    const ushort* __restrict__ xhl,  // (B,N,128) [hi|lo]
    const float* __restrict__ xx,    // (B,N)
    u32* __restrict__ Dm,            // (g,N,N) mapped u32
    int b0, int gshift, int distBlocks,
    const float* __restrict__ xfeat, // (B,N,64)
    const float* __restrict__ w,     // (O,128)
    float* __restrict__ uc) {        // (B,N,2O)
  __shared__ float4 Ws[O * 16];

  if ((int)blockIdx.x < distBlocks) {
    // ----- distance part -----
    int bid = blockIdx.x;
    int b, tile;
    if (gshift >= 0) {
      int xcd = bid & 7;
      int rest = bid >> 3;
      int bl = rest & ((1 << gshift) - 1);
      tile = rest >> gshift;
      b = b0 + xcd + (bl << 3);
    } else {
      b = b0 + (bid >> 6);
      tile = bid & 63;
    }
    int dloc = b - b0;
    int wv = threadIdx.x >> 6;
    int lane = threadIdx.x & 63;
    int wm = wv >> 1, wn = wv & 1;
    int i0 = (tile >> 3) * 128 + wm * 64;
    int j0 = (tile & 7) * 128 + wn * 64;
    int r16 = lane & 15;
    int kg = lane >> 4;

    const ushort* base = xhl + (size_t)b * NN * 128;
    f32x4 acc[4][4];   // acc[tj][ti]: j = j0+tj*16+kg*4+r, i = i0+ti*16+r16
    #pragma unroll
    for (int tj = 0; tj < 4; ++tj)
      #pragma unroll
      for (int ti = 0; ti < 4; ++ti) acc[tj][ti] = (f32x4){0.f, 0.f, 0.f, 0.f};

    #pragma unroll
    for (int ks = 0; ks < 2; ++ks) {
      int k0 = ks * 32 + kg * 8;
      bf16x8 ah[4], al[4], bh[4], bl[4];
      #pragma unroll
      for (int tj = 0; tj < 4; ++tj) {
        const ushort* pr = base + (size_t)(j0 + tj * 16 + r16) * 128 + k0;
        ah[tj] = *(const bf16x8*)pr;
        al[tj] = *(const bf16x8*)(pr + 64);
      }
      #pragma unroll
      for (int ti = 0; ti < 4; ++ti) {
        const ushort* pr = base + (size_t)(i0 + ti * 16 + r16) * 128 + k0;
        bh[ti] = *(const bf16x8*)pr;
        bl[ti] = *(const bf16x8*)(pr + 64);
      }
      #pragma unroll
      for (int tj = 0; tj < 4; ++tj)
        #pragma unroll
        for (int ti = 0; ti < 4; ++ti) {
          acc[tj][ti] = __builtin_amdgcn_mfma_f32_16x16x32_bf16(ah[tj], bh[ti], acc[tj][ti], 0, 0, 0);
          acc[tj][ti] = __builtin_amdgcn_mfma_f32_16x16x32_bf16(ah[tj], bl[ti], acc[tj][ti], 0, 0, 0);
          acc[tj][ti] = __builtin_amdgcn_mfma_f32_16x16x32_bf16(al[tj], bh[ti], acc[tj][ti], 0, 0, 0);
          acc[tj][ti] = __builtin_amdgcn_mfma_f32_16x16x32_bf16(al[tj], bl[ti], acc[tj][ti], 0, 0, 0);
        }
    }

    const float* xxb = xx + (size_t)b * NN;
    u32* Dg = Dm + (size_t)dloc * NN * NN;
    #pragma unroll
    for (int tj = 0; tj < 4; ++tj) {
      float4 xjv = *(const float4*)(xxb + j0 + tj * 16 + kg * 4);
      #pragma unroll
      for (int ti = 0; ti < 4; ++ti) {
        int irow = i0 + ti * 16 + r16;
        uint4 o;
        o.x = map_m(2.f * acc[tj][ti][0] - xjv.x);
        o.y = map_m(2.f * acc[tj][ti][1] - xjv.y);
        o.z = map_m(2.f * acc[tj][ti][2] - xjv.z);
        o.w = map_m(2.f * acc[tj][ti][3] - xjv.w);
        *(uint4*)(Dg + (size_t)irow * NN + j0 + tj * 16 + kg * 4) = o;
      }
    }
  } else {
    // ----- uc GEMM part: Ws LDS-staged, A read wave-uniform from global (L1 broadcast) -----
    int id = blockIdx.x - distBlocks;
    int part = id >> 10;
    int tile = id & 1023;
    int b = tile >> 5;
    int i0 = (tile & 31) * 32;

    const float4* w4 = (const float4*)w;
    for (int r = threadIdx.x; r < O * 16; r += 256) {
      int rowc = r >> 4, c4 = r & 15;
      float4 v;
      if (part == 0) {
        v = w4[(size_t)rowc * 32 + c4];
      } else {
        float4 lo = w4[(size_t)rowc * 32 + c4];
        float4 hi = w4[(size_t)rowc * 32 + 16 + c4];
        v = make_float4(hi.x - lo.x, hi.y - lo.y, hi.z - lo.z, hi.w - lo.w);
      }
      Ws[(rowc << 4) + (c4 ^ (rowc & 7))] = v;
    }
    __syncthreads();

    int col = threadIdx.x % O;
    int pg = threadIdx.x / O;
    constexpr int PPT = 32 * O / 256;
    float4 wc[16];
    #pragma unroll
    for (int c4 = 0; c4 < 16; ++c4) wc[c4] = Ws[(col << 4) + (c4 ^ (col & 7))];

    const float4* xa = (const float4*)(xfeat + ((size_t)b * NN + i0) * CC);
    #pragma unroll
    for (int pp = 0; pp < PPT; ++pp) {
      int p = pg * PPT + pp;
      float acc = 0.f;
      #pragma unroll
      for (int c4 = 0; c4 < 16; ++c4) {
        float4 a = xa[(p << 4) + c4];   // wave-uniform address -> broadcast
        acc += a.x * wc[c4].x; acc += a.y * wc[c4].y;
        acc += a.z * wc[c4].z; acc += a.w * wc[c4].w;
      }
      uc[((size_t)b * NN + i0 + p) * (2 * O) + part * O + col] = acc;
    }
  }
}

// ---------------- wave-per-row top-20 over u32 m ----------------
__global__ __launch_bounds__(256) void topk_kernel(
    const u32* __restrict__ Dm, int* __restrict__ oidx, int b0) {
  __shared__ double sb[4][64];
  int wslot = threadIdx.x >> 6;
  int wid = (blockIdx.x << 2) + wslot;
  int lane = threadIdx.x & 63;
  int row = wid & (NN - 1);
  int bg = wid >> 10;

  const uint4* dp = (const uint4*)(Dm + ((size_t)bg * NN + row) * NN);
  u32 m[16];
  #pragma unroll
  for (int q = 0; q < 4; ++q) {
    uint4 v = dp[q * 64 + lane];
    m[q * 4 + 0] = v.x; m[q * 4 + 1] = v.y; m[q * 4 + 2] = v.z; m[q * 4 + 3] = v.w;
  }
  topk_sel(m, lane, &sb[wslot][0], oidx + ((size_t)(b0 + bg) * NN + row) * KK);
}

// ---------------- merged layer-1: fused C=3 dist+top-20 (blocks < 8192) + uc3 ----------------
__global__ __launch_bounds__(256) void tu3_kernel(
    const float* __restrict__ x,   // (B,N,3)
    const float* __restrict__ xT,  // (B,3,N)
    const float* __restrict__ xx,  // (B,N)
    int* __restrict__ oidx,
    const float* __restrict__ w1,
    float* __restrict__ uc) {
  __shared__ double sb[4][64];
  if ((int)blockIdx.x < 8192) {
    int wslot = threadIdx.x >> 6;
    int wid = ((int)blockIdx.x << 2) + wslot;
    int lane = threadIdx.x & 63;
    int row = wid & (NN - 1);
    int b = wid >> 10;

    const float* xr = x + ((size_t)b * NN + row) * 3;
    float x0 = xr[0], x1 = xr[1], x2 = xr[2];
    const float* xTb = xT + (size_t)b * 3 * NN;
    const float* xxb = xx + (size_t)b * NN;

    u32 m[16];
    #pragma unroll
    for (int q = 0; q < 4; ++q) {
      int f4i = q * 64 + lane;
      float4 a  = ((const float4*)xTb)[f4i];
      float4 bv = ((const float4*)(xTb + NN))[f4i];
      float4 c  = ((const float4*)(xTb + 2 * NN))[f4i];
      float4 xj = ((const float4*)xxb)[f4i];
      float d0 = 0.f; d0 += x0 * a.x; d0 += x1 * bv.x; d0 += x2 * c.x;
      float d1 = 0.f; d1 += x0 * a.y; d1 += x1 * bv.y; d1 += x2 * c.y;
      float d2 = 0.f; d2 += x0 * a.z; d2 += x1 * bv.z; d2 += x2 * c.z;
      float d3 = 0.f; d3 += x0 * a.w; d3 += x1 * bv.w; d3 += x2 * c.w;
      m[q * 4 + 0] = map_m(2.f * d0 - xj.x);
      m[q * 4 + 1] = map_m(2.f * d1 - xj.y);
      m[q * 4 + 2] = map_m(2.f * d2 - xj.z);
      m[q * 4 + 3] = map_m(2.f * d3 - xj.w);
    }
    topk_sel(m, lane, &sb[wslot][0], oidx + ((size_t)b * NN + row) * KK);
  } else {
    int t = ((int)blockIdx.x - 8192) * 256 + threadIdx.x;   // B*N*128
    int col = t & 127;
    int i = (t >> 7) & (NN - 1);
    int b = t >> 17;
    const float* xr = x + ((size_t)b * NN + i) * 3;
    float x0 = xr[0], x1 = xr[1], x2 = xr[2];
    float r;
    if (col < 64) {
      const float* wr = w1 + col * 6;
      r = wr[0] * x0 + wr[1] * x1 + wr[2] * x2;
    } else {
      const float* wr = w1 + (col - 64) * 6;
      r = (wr[3] - wr[0]) * x0 + (wr[4] - wr[1]) * x1 + (wr[5] - wr[2]) * x2;
    }
    uc[(size_t)t] = r;
  }
}

// ---- gather-max + BN/ReLU + global-pool + (NEXT) y/xhl/xx prep. XCD-swizzled blocks. ----
template<int O, bool NEXT>
__global__ __launch_bounds__(256) void gmp_kernel(
    const float* __restrict__ uc,   // (B,N,2O)
    const int*   __restrict__ idx,  // (B,N,K)
    const float* __restrict__ g,
    const float* __restrict__ bb,
    float* __restrict__ y,          // (B,N,O)
    u32* __restrict__ pooled,       // (B,320) u32 bit patterns (all >= 0)
    int ooff,
    ushort* __restrict__ xhl,       // (B,N,128) [hi|lo]   (NEXT only)
    float* __restrict__ xx) {       // (B,N)               (NEXT only)
  constexpr int O4 = O / 4;
  constexpr int PPB = 256 / O4;
  int bid = blockIdx.x;
  int xcd = bid & 7;
  int rest = bid >> 3;
  int bgrp = rest & 3;
  int jblk = rest >> 2;
  int b = xcd + (bgrp << 3);
  int o4 = threadIdx.x & (O4 - 1);
  int i = jblk * PPB + (threadIdx.x >> (O == 64 ? 4 : 5));

  const int* irow = idx + ((size_t)b * NN + i) * KK;
  int jj[KK];
  #pragma unroll
  for (int k = 0; k < KK; ++k) jj[k] = irow[k];

  const float* ucb = uc + (size_t)b * NN * (2 * O);
  float4 vm = make_float4(-INFINITY, -INFINITY, -INFINITY, -INFINITY);
  #pragma unroll
  for (int k = 0; k < KK; ++k) {
    float4 v = *(const float4*)(ucb + (size_t)jj[k] * (2 * O) + o4 * 4);
    vm.x = fmaxf(vm.x, v.x); vm.y = fmaxf(vm.y, v.y);
    vm.z = fmaxf(vm.z, v.z); vm.w = fmaxf(vm.w, v.w);
  }
  float4 c0 = *(const float4*)(ucb + (size_t)i * (2 * O) + O + o4 * 4);
  float4 gv = ((const float4*)g)[o4];
  float4 bv = ((const float4*)bb)[o4];
  const float inv = 1.0f / sqrtf(1.0f + EPSF);
  float4 o;
  o.x = fmaxf((gv.x * inv) * (vm.x + c0.x) + bv.x, 0.f);
  o.y = fmaxf((gv.y * inv) * (vm.y + c0.y) + bv.y, 0.f);
  o.z = fmaxf((gv.z * inv) * (vm.z + c0.z) + bv.z, 0.f);
  o.w = fmaxf((gv.w * inv) * (vm.w + c0.w) + bv.w, 0.f);

  if constexpr (NEXT) {
    *(float4*)(y + ((size_t)b * NN + i) * O + o4 * 4) = o;
    ushort4 hi, lo;
    u32 q0 = __float_as_uint(o.x); hi.x = q0 >> 16;
    u32 q1 = __float_as_uint(o.y); hi.y = q1 >> 16;
    u32 q2 = __float_as_uint(o.z); hi.z = q2 >> 16;
    u32 q3 = __float_as_uint(o.w); hi.w = q3 >> 16;
    lo.x = __float_as_uint(o.x - __uint_as_float(q0 & 0xFFFF0000u)) >> 16;
    lo.y = __float_as_uint(o.y - __uint_as_float(q1 & 0xFFFF0000u)) >> 16;
    lo.z = __float_as_uint(o.z - __uint_as_float(q2 & 0xFFFF0000u)) >> 16;
    lo.w = __float_as_uint(o.w - __uint_as_float(q3 & 0xFFFF0000u)) >> 16;
    ushort* xr = xhl + ((size_t)b * NN + i) * 128;
    *(ushort4*)(xr + o4 * 4) = hi;
    *(ushort4*)(xr + 64 + o4 * 4) = lo;
    float px = o.x * o.x + o.y * o.y + o.z * o.z + o.w * o.w;
    px += __shfl_xor(px, 1);
    px += __shfl_xor(px, 2);
    px += __shfl_xor(px, 4);
    px += __shfl_xor(px, 8);
    if (o4 == 0) xx[(size_t)b * NN + i] = px;
  }

  __shared__ float4 sm[256];
  sm[threadIdx.x] = o;
  __syncthreads();
  if (threadIdx.x < O4) {
    float4 m = sm[threadIdx.x];
    #pragma unroll
    for (int r = 1; r < PPB; ++r) {
      float4 v = sm[threadIdx.x + r * O4];
      m.x = fmaxf(m.x, v.x); m.y = fmaxf(m.y, v.y);
      m.z = fmaxf(m.z, v.z); m.w = fmaxf(m.w, v.w);
    }
    u32* dst = pooled + (size_t)b * 320 + ooff + threadIdx.x * 4;
    atomicMax(dst + 0, __float_as_uint(m.x));
    atomicMax(dst + 1, __float_as_uint(m.y));
    atomicMax(dst + 2, __float_as_uint(m.z));
    atomicMax(dst + 3, __float_as_uint(m.w));
  }
}

// ---------------- coalesced fc: wave-per-output, LDS-staged input ----------------
template<int IN, int OUT, int OPW, bool BNRELU>
__global__ __launch_bounds__(256) void fcw_kernel(
    const float* __restrict__ in, const float* __restrict__ W,
    const float* __restrict__ lb, const float* __restrict__ g,
    const float* __restrict__ bbias, float* __restrict__ out) {
  int b = blockIdx.x;
  int oc = blockIdx.y;
  __shared__ float sIn[IN];
  for (int r = threadIdx.x; r < IN; r += 256) sIn[r] = in[(size_t)b * IN + r];
  __syncthreads();
  int w = threadIdx.x >> 6, lane = threadIdx.x & 63;
  constexpr int RPL = IN / 64;
  for (int ii = 0; ii < OPW; ++ii) {
    int o = (oc * 4 + w) * OPW + ii;
    const float* wr = W + (size_t)o * IN;
    float acc = 0.f;
    #pragma unroll
    for (int r = 0; r < RPL; ++r) acc += wr[r * 64 + lane] * sIn[r * 64 + lane];
    #pragma unroll
    for (int m = 32; m >= 1; m >>= 1) acc += __shfl_xor(acc, m);
    if (lane == 0) {
      acc += lb[o];
      if (BNRELU) {
        float s = g[o] * (1.0f / sqrtf(1.0f + EPSF));
        acc = fmaxf(acc * s + bbias[o], 0.0f);
      }
      out[(size_t)b * OUT + o] = acc;
    }
  }
}

extern "C" void kernel_launch(void* const* d_in, const int* in_sizes, int n_in,
                              void* d_out, int out_size, void* d_ws, size_t ws_size,
                              hipStream_t stream) {
  const float* x   = (const float*)d_in[0];
  const float* w1  = (const float*)d_in[1];
  const float* g1  = (const float*)d_in[2];
  const float* b1  = (const float*)d_in[3];
  const float* w2  = (const float*)d_in[4];
  const float* g2  = (const float*)d_in[5];
  const float* b2  = (const float*)d_in[6];
  const float* w3  = (const float*)d_in[7];
  const float* g3  = (const float*)d_in[8];
  const float* b3  = (const float*)d_in[9];
  const float* w4  = (const float*)d_in[10];
  const float* g4  = (const float*)d_in[11];
  const float* b4  = (const float*)d_in[12];
  const float* lw1 = (const float*)d_in[13];
  const float* lb1 = (const float*)d_in[14];
  const float* g5  = (const float*)d_in[15];
  const float* b5  = (const float*)d_in[16];
  const float* lw2 = (const float*)d_in[17];
  const float* lb2 = (const float*)d_in[18];
  const float* g6  = (const float*)d_in[19];
  const float* b6  = (const float*)d_in[20];
  const float* lw3 = (const float*)d_in[21];
  const float* lb3 = (const float*)d_in[22];
  float* out = (float*)d_out;

  char* ws = (char*)d_ws;
  size_t off = 0;
  auto alloc = [&](size_t bytes) -> char* {
    char* p = ws + off;
    off += (bytes + 255) & ~255ULL;
    return p;
  };
  int*   idx    = (int*)  alloc((size_t)BB * NN * KK * 4);
  float* xx     = (float*)alloc((size_t)BB * NN * 4);
  float* xT0    = (float*)alloc((size_t)BB * 3 * NN * 4);
  float* bufA   = (float*)alloc((size_t)BB * NN * 64 * 4);
  float* bufB   = (float*)alloc((size_t)BB * NN * 64 * 4);
  float* pooled = (float*)alloc((size_t)BB * 320 * 4);
  float* h1     = (float*)alloc((size_t)BB * 1024 * 4);
  float* h2     = (float*)alloc((size_t)BB * 512 * 4);
  float* uc     = (float*)alloc((size_t)BB * NN * 256 * 4);
  ushort* xhl   = (ushort*)alloc((size_t)BB * NN * 128 * 2);

  size_t dbytes_per_b = (size_t)NN * NN * 4;
  size_t rem = (ws_size > off) ? (ws_size - off) : 0;
  int gmax = (int)(rem / dbytes_per_b);
  if (gmax > 8) gmax = 8;   // keep Dm (33 MB) L3-resident across write->read->overwrite
  int gp2 = 1;
  while (gp2 * 2 <= gmax) gp2 <<= 1;
  gmax = gp2 < 1 ? 1 : gp2;
  u32* Dm = (u32*)alloc((size_t)gmax * dbytes_per_b);

  int gshift = -1;
  if (gmax >= 8) {
    int gper = gmax >> 3;
    gshift = 0;
    while ((1 << gshift) < gper) ++gshift;
  }

  dim3 blk(256);
  int bn_blocks = (BB * NN + 255) / 256;

  // per layer: [dist(+ucGEMM on first group) merged] -> topk, per batch-group
  auto layer64 = [&](const float* feat, const float* w, const float* gg, const float* bbv,
                     float* yout, int ooff, bool next) {
    for (int b0 = 0; b0 < BB; b0 += gmax) {
      int distBlocks = gmax * 64;
      int ucBlocks = (b0 == 0) ? 2048 : 0;
      ducp_kernel<64><<<distBlocks + ucBlocks, blk, 0, stream>>>(
          xhl, xx, Dm, b0, gshift, distBlocks, feat, w, uc);
      topk_kernel<<<(gmax * NN) / 4, blk, 0, stream>>>(Dm, idx, b0);
    }
    if (next)
      gmp_kernel<64, true><<<(BB * NN * 16) / 256, blk, 0, stream>>>(
          uc, idx, gg, bbv, yout, (u32*)pooled, ooff, xhl, xx);
    else
      gmp_kernel<64, false><<<(BB * NN * 16) / 256, blk, 0, stream>>>(
          uc, idx, gg, bbv, yout, (u32*)pooled, ooff, nullptr, nullptr);
  };

  // ---- layer 1 (C=3 -> 64) ----
  t3xx_kernel<<<bn_blocks, blk, 0, stream>>>(x, xT0, xx, pooled);
  tu3_kernel<<<8192 + 16384, blk, 0, stream>>>(x, xT0, xx, idx, w1, uc);
  gmp_kernel<64, true><<<(BB * NN * 16) / 256, blk, 0, stream>>>(
      uc, idx, g1, b1, bufA, (u32*)pooled, 0, xhl, xx);

  // ---- layer 2 (64 -> 64) ----
  layer64(bufA, w2, g2, b2, bufB, 64, true);

  // ---- layer 3 (64 -> 64) ----
  layer64(bufB, w3, g3, b3, bufA, 128, true);

  // ---- layer 4 (64 -> 128) ----
  for (int b0 = 0; b0 < BB; b0 += gmax) {
    int distBlocks = gmax * 64;
    int ucBlocks = (b0 == 0) ? 2048 : 0;
    ducp_kernel<128><<<distBlocks + ucBlocks, blk, 0, stream>>>(
        xhl, xx, Dm, b0, gshift, distBlocks, bufA, w4, uc);
    topk_kernel<<<(gmax * NN) / 4, blk, 0, stream>>>(Dm, idx, b0);
  }
  gmp_kernel<128, false><<<(BB * NN * 32) / 256, blk, 0, stream>>>(
      uc, idx, g4, b4, bufB, (u32*)pooled, 192, nullptr, nullptr);

  // ---- classifier ----
  fcw_kernel<320, 1024, 32, true><<<dim3(BB, 8), blk, 0, stream>>>(pooled, lw1, lb1, g5, b5, h1);
  fcw_kernel<1024, 512, 16, true><<<dim3(BB, 8), blk, 0, stream>>>(h1, lw2, lb2, g6, b6, h2);
  fcw_kernel<512, 40, 10, false><<<dim3(BB, 1), blk, 0, stream>>>(h2, lw3, lb3, nullptr, nullptr, out);
}

// Round 17
// 424.439 us; speedup vs baseline: 1.5421x; 1.5421x over previous
//
#include <hip/hip_runtime.h>
#include <math.h>

#define BB 32
#define NN 1024
#define KK 20
typedef unsigned long long u64;
typedef unsigned int u32;
typedef unsigned short ushort;
static constexpr float EPSF = 1e-5f;

typedef __attribute__((ext_vector_type(8))) short bf16x8;
typedef __attribute__((ext_vector_type(4))) float f32x4;
typedef __attribute__((ext_vector_type(4))) u32 u32x4;

// ---------------- fused transpose (B,N,3)->(B,3,N) + xx + pooled zero ----------------
__global__ void t3xx_kernel(const float* __restrict__ x, float* __restrict__ xT,
                            float* __restrict__ xx, float* __restrict__ pooled) {
  int t = blockIdx.x * blockDim.x + threadIdx.x;
  if (t >= BB * NN) return;
  if (t < BB * 320) pooled[t] = 0.0f;
  int b = t >> 10, i = t & (NN - 1);
  float v0 = x[(size_t)t * 3 + 0], v1 = x[(size_t)t * 3 + 1], v2 = x[(size_t)t * 3 + 2];
  xT[((size_t)b * 3 + 0) * NN + i] = v0;
  xT[((size_t)b * 3 + 1) * NN + i] = v1;
  xT[((size_t)b * 3 + 2) * NN + i] = v2;
  float s = 0.f;
  s += v0 * v0; s += v1 * v1; s += v2 * v2;
  xx[t] = s;
}

// ---------------- monotone f32 -> u32 order map ----------------
__device__ __forceinline__ u32 map_m(float d) {
  u32 bits = __float_as_uint(d);
  return bits ^ (u32)(((int)bits >> 31) | 0x80000000);
}

__device__ __forceinline__ double shflxd(double v, int m) {
  long long u = __double_as_longlong(v);
  int lo = (int)(u & 0xFFFFFFFFll);
  int hi = (int)(((u64)u) >> 32);
  lo = __shfl_xor(lo, m);
  hi = __shfl_xor(hi, m);
  return __longlong_as_double(((long long)hi << 32) | (u32)lo);
}

// descending bitonic sorts
__device__ __forceinline__ u32 lane_sort64_u32(u32 v, int lane) {
  #pragma unroll
  for (int kk = 2; kk <= 64; kk <<= 1)
    #pragma unroll
    for (int j = kk >> 1; j > 0; j >>= 1) {
      u32 pv = (u32)__shfl_xor((int)v, j);
      bool keepMax = (((lane & j) == 0) == ((lane & kk) == 0));
      u32 mx = v > pv ? v : pv, mn = v > pv ? pv : v;
      v = keepMax ? mx : mn;
    }
  return v;
}

__device__ __forceinline__ double lane_sort64(double v, int lane) {
  #pragma unroll
  for (int kk = 2; kk <= 64; kk <<= 1)
    #pragma unroll
    for (int j = kk >> 1; j > 0; j >>= 1) {
      double pv = shflxd(v, j);
      bool keepMax = (((lane & j) == 0) == ((lane & kk) == 0));
      v = keepMax ? fmax(v, pv) : fmin(v, pv);
    }
  return v;
}

__device__ __forceinline__ double lane_sort32(double v, int lane) {
  #pragma unroll
  for (int kk = 2; kk <= 32; kk <<= 1)
    #pragma unroll
    for (int j = kk >> 1; j > 0; j >>= 1) {
      double pv = shflxd(v, j);
      bool keepMax = (((lane & j) == 0) == ((lane & kk) == 0));
      v = keepMax ? fmax(v, pv) : fmin(v, pv);
    }
  return v;
}

__device__ __forceinline__ void key_decode_write(double res, int lane, int* __restrict__ orow) {
  if (lane < KK) {
    double md = trunc(res * (1.0 / 1024.0));
    double rd = fma(md, -1024.0, res);
    orow[lane] = 1023 - (int)rd;
  }
}

// u32 first-stage filter + f64 survivor sort. m[e], e=(q<<2)|c: j = q*256 + lane*4 + c
__device__ __forceinline__ void topk_sel(u32 (&m)[16], int lane,
                                         volatile double* __restrict__ sb,
                                         int* __restrict__ orow) {
  u32 h = m[0];
  #pragma unroll
  for (int e = 1; e < 16; ++e) h = m[e] > h ? m[e] : h;
  u32 sh = lane_sort64_u32(h, lane);
  u32 T = (u32)__shfl((int)sh, KK - 1);

  int cnt = 0;
  #pragma unroll
  for (int e = 0; e < 16; ++e) cnt += (m[e] >= T) ? 1 : 0;
  int scan = cnt;
  #pragma unroll
  for (int d = 1; d < 64; d <<= 1) {
    int nv = __shfl_up(scan, d);
    if (lane >= d) scan += nv;
  }
  int total = __shfl(scan, 63);
  double based = (double)(1023 - lane * 4);

  if (total <= 64) {
    int ofs = scan - cnt;
    sb[lane] = 0.0;
    #pragma unroll
    for (int e = 0; e < 16; ++e)
      if (m[e] >= T) {
        double kd = fma((double)m[e], 1024.0, based - (double)((e >> 2) * 256 + (e & 3)));
        sb[ofs++] = kd;
      }
    double v = sb[lane];
    v = (total <= 32) ? lane_sort32(v, lane) : lane_sort64(v, lane);
    key_decode_write(v, lane, orow);
  } else {
    // exact fallback (tie-heavy rows): f64-key tournament
    double k[16];
    #pragma unroll
    for (int e = 0; e < 16; ++e)
      k[e] = fma((double)m[e], 1024.0, based - (double)((e >> 2) * 256 + (e & 3)));
    double lm = k[0];
    #pragma unroll
    for (int e = 1; e < 16; ++e) lm = fmax(lm, k[e]);
    double res = 0.0;
    for (int t = 0; t < KK; ++t) {
      double w = lm;
      #pragma unroll
      for (int mm = 1; mm < 64; mm <<= 1) w = fmax(w, shflxd(w, mm));
      if (lane == t) res = w;
      bool win = (lm == w);
      #pragma unroll
      for (int e = 0; e < 16; ++e) k[e] = (k[e] == w) ? 0.0 : k[e];
      if (win) {
        double n0 = fmax(k[0], k[1]);
        #pragma unroll
        for (int e = 2; e < 16; ++e) n0 = fmax(n0, k[e]);
        lm = n0;
      }
    }
    key_decode_write(res, lane, orow);
  }
}

// ---------------- merged: MFMA dist (u32-m output, XCD-swizzled) + uc GEMM ----------------
// dist: operand-swapped MFMA -> nontemporal uint4 stores (write-once stream, keep L2 for xhl).
#define CC 64
template<int O>
__global__ __launch_bounds__(256) void ducp_kernel(
    const ushort* __restrict__ xhl,  // (B,N,128) [hi|lo]
    const float* __restrict__ xx,    // (B,N)
    u32* __restrict__ Dm,            // (g,N,N) mapped u32
    int b0, int gshift, int distBlocks,
    const float* __restrict__ xfeat, // (B,N,64)
    const float* __restrict__ w,     // (O,128)
    float* __restrict__ uc) {        // (B,N,2O)
  __shared__ float4 Ws[O * 16];
  __shared__ float4 As[32 * 16];

  if ((int)blockIdx.x < distBlocks) {
    // ----- distance part -----
    int bid = blockIdx.x;
    int b, tile;
    if (gshift >= 0) {
      int xcd = bid & 7;
      int rest = bid >> 3;
      int bl = rest & ((1 << gshift) - 1);
      tile = rest >> gshift;
      b = b0 + xcd + (bl << 3);
    } else {
      b = b0 + (bid >> 6);
      tile = bid & 63;
    }
    int dloc = b - b0;
    int wv = threadIdx.x >> 6;
    int lane = threadIdx.x & 63;
    int wm = wv >> 1, wn = wv & 1;
    int i0 = (tile >> 3) * 128 + wm * 64;
    int j0 = (tile & 7) * 128 + wn * 64;
    int r16 = lane & 15;
    int kg = lane >> 4;

    const ushort* base = xhl + (size_t)b * NN * 128;
    f32x4 acc[4][4];   // acc[tj][ti]: j = j0+tj*16+kg*4+r, i = i0+ti*16+r16
    #pragma unroll
    for (int tj = 0; tj < 4; ++tj)
      #pragma unroll
      for (int ti = 0; ti < 4; ++ti) acc[tj][ti] = (f32x4){0.f, 0.f, 0.f, 0.f};

    #pragma unroll
    for (int ks = 0; ks < 2; ++ks) {
      int k0 = ks * 32 + kg * 8;
      bf16x8 ah[4], al[4], bh[4], bl[4];
      #pragma unroll
      for (int tj = 0; tj < 4; ++tj) {
        const ushort* pr = base + (size_t)(j0 + tj * 16 + r16) * 128 + k0;
        ah[tj] = *(const bf16x8*)pr;
        al[tj] = *(const bf16x8*)(pr + 64);
      }
      #pragma unroll
      for (int ti = 0; ti < 4; ++ti) {
        const ushort* pr = base + (size_t)(i0 + ti * 16 + r16) * 128 + k0;
        bh[ti] = *(const bf16x8*)pr;
        bl[ti] = *(const bf16x8*)(pr + 64);
      }
      #pragma unroll
      for (int tj = 0; tj < 4; ++tj)
        #pragma unroll
        for (int ti = 0; ti < 4; ++ti) {
          acc[tj][ti] = __builtin_amdgcn_mfma_f32_16x16x32_bf16(ah[tj], bh[ti], acc[tj][ti], 0, 0, 0);
          acc[tj][ti] = __builtin_amdgcn_mfma_f32_16x16x32_bf16(ah[tj], bl[ti], acc[tj][ti], 0, 0, 0);
          acc[tj][ti] = __builtin_amdgcn_mfma_f32_16x16x32_bf16(al[tj], bh[ti], acc[tj][ti], 0, 0, 0);
          acc[tj][ti] = __builtin_amdgcn_mfma_f32_16x16x32_bf16(al[tj], bl[ti], acc[tj][ti], 0, 0, 0);
        }
    }

    const float* xxb = xx + (size_t)b * NN;
    u32* Dg = Dm + (size_t)dloc * NN * NN;
    #pragma unroll
    for (int tj = 0; tj < 4; ++tj) {
      float4 xjv = *(const float4*)(xxb + j0 + tj * 16 + kg * 4);
      #pragma unroll
      for (int ti = 0; ti < 4; ++ti) {
        int irow = i0 + ti * 16 + r16;
        u32x4 o;
        o.x = map_m(2.f * acc[tj][ti][0] - xjv.x);
        o.y = map_m(2.f * acc[tj][ti][1] - xjv.y);
        o.z = map_m(2.f * acc[tj][ti][2] - xjv.z);
        o.w = map_m(2.f * acc[tj][ti][3] - xjv.w);
        __builtin_nontemporal_store(o, (u32x4*)(Dg + (size_t)irow * NN + j0 + tj * 16 + kg * 4));
      }
    }
  } else {
    // ----- uc GEMM part (r15-proven LDS staging) -----
    int id = blockIdx.x - distBlocks;
    int part = id >> 10;
    int tile = id & 1023;
    int b = tile >> 5;
    int i0 = (tile & 31) * 32;

    const float4* w4 = (const float4*)w;
    for (int r = threadIdx.x; r < O * 16; r += 256) {
      int rowc = r >> 4, c4 = r & 15;
      float4 v;
      if (part == 0) {
        v = w4[(size_t)rowc * 32 + c4];
      } else {
        float4 lo = w4[(size_t)rowc * 32 + c4];
        float4 hi = w4[(size_t)rowc * 32 + 16 + c4];
        v = make_float4(hi.x - lo.x, hi.y - lo.y, hi.z - lo.z, hi.w - lo.w);
      }
      Ws[(rowc << 4) + (c4 ^ (rowc & 7))] = v;
    }
    const float4* xa = (const float4*)(xfeat + ((size_t)b * NN + i0) * CC);
    for (int r = threadIdx.x; r < 32 * 16; r += 256) As[r] = xa[r];
    __syncthreads();

    int col = threadIdx.x % O;
    int pg = threadIdx.x / O;
    constexpr int PPT = 32 * O / 256;
    float4 wc[16];
    #pragma unroll
    for (int c4 = 0; c4 < 16; ++c4) wc[c4] = Ws[(col << 4) + (c4 ^ (col & 7))];

    #pragma unroll
    for (int pp = 0; pp < PPT; ++pp) {
      int p = pg * PPT + pp;
      float acc = 0.f;
      #pragma unroll
      for (int c4 = 0; c4 < 16; ++c4) {
        float4 a = As[(p << 4) + c4];
        acc += a.x * wc[c4].x; acc += a.y * wc[c4].y;
        acc += a.z * wc[c4].z; acc += a.w * wc[c4].w;
      }
      uc[((size_t)b * NN + i0 + p) * (2 * O) + part * O + col] = acc;
    }
  }
}

// ---------------- wave-per-row top-20 over u32 m (nontemporal Dm reads) ----------------
__global__ __launch_bounds__(256) void topk_kernel(
    const u32* __restrict__ Dm, int* __restrict__ oidx, int b0) {
  __shared__ double sb[4][64];
  int wslot = threadIdx.x >> 6;
  int wid = (blockIdx.x << 2) + wslot;
  int lane = threadIdx.x & 63;
  int row = wid & (NN - 1);
  int bg = wid >> 10;

  const u32x4* dp = (const u32x4*)(Dm + ((size_t)bg * NN + row) * NN);
  u32 m[16];
  #pragma unroll
  for (int q = 0; q < 4; ++q) {
    u32x4 v = __builtin_nontemporal_load(dp + q * 64 + lane);
    m[q * 4 + 0] = v.x; m[q * 4 + 1] = v.y; m[q * 4 + 2] = v.z; m[q * 4 + 3] = v.w;
  }
  topk_sel(m, lane, &sb[wslot][0], oidx + ((size_t)(b0 + bg) * NN + row) * KK);
}

// ---------------- merged layer-1: fused C=3 dist+top-20 (blocks < 8192) + uc3 ----------------
__global__ __launch_bounds__(256) void tu3_kernel(
    const float* __restrict__ x,   // (B,N,3)
    const float* __restrict__ xT,  // (B,3,N)
    const float* __restrict__ xx,  // (B,N)
    int* __restrict__ oidx,
    const float* __restrict__ w1,
    float* __restrict__ uc) {
  __shared__ double sb[4][64];
  if ((int)blockIdx.x < 8192) {
    int wslot = threadIdx.x >> 6;
    int wid = ((int)blockIdx.x << 2) + wslot;
    int lane = threadIdx.x & 63;
    int row = wid & (NN - 1);
    int b = wid >> 10;

    const float* xr = x + ((size_t)b * NN + row) * 3;
    float x0 = xr[0], x1 = xr[1], x2 = xr[2];
    const float* xTb = xT + (size_t)b * 3 * NN;
    const float* xxb = xx + (size_t)b * NN;

    u32 m[16];
    #pragma unroll
    for (int q = 0; q < 4; ++q) {
      int f4i = q * 64 + lane;
      float4 a  = ((const float4*)xTb)[f4i];
      float4 bv = ((const float4*)(xTb + NN))[f4i];
      float4 c  = ((const float4*)(xTb + 2 * NN))[f4i];
      float4 xj = ((const float4*)xxb)[f4i];
      float d0 = 0.f; d0 += x0 * a.x; d0 += x1 * bv.x; d0 += x2 * c.x;
      float d1 = 0.f; d1 += x0 * a.y; d1 += x1 * bv.y; d1 += x2 * c.y;
      float d2 = 0.f; d2 += x0 * a.z; d2 += x1 * bv.z; d2 += x2 * c.z;
      float d3 = 0.f; d3 += x0 * a.w; d3 += x1 * bv.w; d3 += x2 * c.w;
      m[q * 4 + 0] = map_m(2.f * d0 - xj.x);
      m[q * 4 + 1] = map_m(2.f * d1 - xj.y);
      m[q * 4 + 2] = map_m(2.f * d2 - xj.z);
      m[q * 4 + 3] = map_m(2.f * d3 - xj.w);
    }
    topk_sel(m, lane, &sb[wslot][0], oidx + ((size_t)b * NN + row) * KK);
  } else {
    int t = ((int)blockIdx.x - 8192) * 256 + threadIdx.x;   // B*N*128
    int col = t & 127;
    int i = (t >> 7) & (NN - 1);
    int b = t >> 17;
    const float* xr = x + ((size_t)b * NN + i) * 3;
    float x0 = xr[0], x1 = xr[1], x2 = xr[2];
    float r;
    if (col < 64) {
      const float* wr = w1 + col * 6;
      r = wr[0] * x0 + wr[1] * x1 + wr[2] * x2;
    } else {
      const float* wr = w1 + (col - 64) * 6;
      r = (wr[3] - wr[0]) * x0 + (wr[4] - wr[1]) * x1 + (wr[5] - wr[2]) * x2;
    }
    uc[(size_t)t] = r;
  }
}

// ---- gather-max + BN/ReLU + global-pool + (NEXT) y/xhl/xx prep. XCD-swizzled blocks. ----
template<int O, bool NEXT>
__global__ __launch_bounds__(256) void gmp_kernel(
    const float* __restrict__ uc,   // (B,N,2O)
    const int*   __restrict__ idx,  // (B,N,K)
    const float* __restrict__ g,
    const float* __restrict__ bb,
    float* __restrict__ y,          // (B,N,O)
    u32* __restrict__ pooled,       // (B,320) u32 bit patterns (all >= 0)
    int ooff,
    ushort* __restrict__ xhl,       // (B,N,128) [hi|lo]   (NEXT only)
    float* __restrict__ xx) {       // (B,N)               (NEXT only)
  constexpr int O4 = O / 4;
  constexpr int PPB = 256 / O4;
  int bid = blockIdx.x;
  int xcd = bid & 7;
  int rest = bid >> 3;
  int bgrp = rest & 3;
  int jblk = rest >> 2;
  int b = xcd + (bgrp << 3);
  int o4 = threadIdx.x & (O4 - 1);
  int i = jblk * PPB + (threadIdx.x >> (O == 64 ? 4 : 5));

  const int* irow = idx + ((size_t)b * NN + i) * KK;
  int jj[KK];
  #pragma unroll
  for (int k = 0; k < KK; ++k) jj[k] = irow[k];

  const float* ucb = uc + (size_t)b * NN * (2 * O);
  float4 vm = make_float4(-INFINITY, -INFINITY, -INFINITY, -INFINITY);
  #pragma unroll
  for (int k = 0; k < KK; ++k) {
    float4 v = *(const float4*)(ucb + (size_t)jj[k] * (2 * O) + o4 * 4);
    vm.x = fmaxf(vm.x, v.x); vm.y = fmaxf(vm.y, v.y);
    vm.z = fmaxf(vm.z, v.z); vm.w = fmaxf(vm.w, v.w);
  }
  float4 c0 = *(const float4*)(ucb + (size_t)i * (2 * O) + O + o4 * 4);
  float4 gv = ((const float4*)g)[o4];
  float4 bv = ((const float4*)bb)[o4];
  const float inv = 1.0f / sqrtf(1.0f + EPSF);
  float4 o;
  o.x = fmaxf((gv.x * inv) * (vm.x + c0.x) + bv.x, 0.f);
  o.y = fmaxf((gv.y * inv) * (vm.y + c0.y) + bv.y, 0.f);
  o.z = fmaxf((gv.z * inv) * (vm.z + c0.z) + bv.z, 0.f);
  o.w = fmaxf((gv.w * inv) * (vm.w + c0.w) + bv.w, 0.f);

  if constexpr (NEXT) {
    *(float4*)(y + ((size_t)b * NN + i) * O + o4 * 4) = o;
    ushort4 hi, lo;
    u32 q0 = __float_as_uint(o.x); hi.x = q0 >> 16;
    u32 q1 = __float_as_uint(o.y); hi.y = q1 >> 16;
    u32 q2 = __float_as_uint(o.z); hi.z = q2 >> 16;
    u32 q3 = __float_as_uint(o.w); hi.w = q3 >> 16;
    lo.x = __float_as_uint(o.x - __uint_as_float(q0 & 0xFFFF0000u)) >> 16;
    lo.y = __float_as_uint(o.y - __uint_as_float(q1 & 0xFFFF0000u)) >> 16;
    lo.z = __float_as_uint(o.z - __uint_as_float(q2 & 0xFFFF0000u)) >> 16;
    lo.w = __float_as_uint(o.w - __uint_as_float(q3 & 0xFFFF0000u)) >> 16;
    ushort* xr = xhl + ((size_t)b * NN + i) * 128;
    *(ushort4*)(xr + o4 * 4) = hi;
    *(ushort4*)(xr + 64 + o4 * 4) = lo;
    float px = o.x * o.x + o.y * o.y + o.z * o.z + o.w * o.w;
    px += __shfl_xor(px, 1);
    px += __shfl_xor(px, 2);
    px += __shfl_xor(px, 4);
    px += __shfl_xor(px, 8);
    if (o4 == 0) xx[(size_t)b * NN + i] = px;
  }

  __shared__ float4 sm[256];
  sm[threadIdx.x] = o;
  __syncthreads();
  if (threadIdx.x < O4) {
    float4 m = sm[threadIdx.x];
    #pragma unroll
    for (int r = 1; r < PPB; ++r) {
      float4 v = sm[threadIdx.x + r * O4];
      m.x = fmaxf(m.x, v.x); m.y = fmaxf(m.y, v.y);
      m.z = fmaxf(m.z, v.z); m.w = fmaxf(m.w, v.w);
    }
    u32* dst = pooled + (size_t)b * 320 + ooff + threadIdx.x * 4;
    atomicMax(dst + 0, __float_as_uint(m.x));
    atomicMax(dst + 1, __float_as_uint(m.y));
    atomicMax(dst + 2, __float_as_uint(m.z));
    atomicMax(dst + 3, __float_as_uint(m.w));
  }
}

// ---------------- coalesced fc: wave-per-output, LDS-staged input ----------------
template<int IN, int OUT, int OPW, bool BNRELU>
__global__ __launch_bounds__(256) void fcw_kernel(
    const float* __restrict__ in, const float* __restrict__ W,
    const float* __restrict__ lb, const float* __restrict__ g,
    const float* __restrict__ bbias, float* __restrict__ out) {
  int b = blockIdx.x;
  int oc = blockIdx.y;
  __shared__ float sIn[IN];
  for (int r = threadIdx.x; r < IN; r += 256) sIn[r] = in[(size_t)b * IN + r];
  __syncthreads();
  int w = threadIdx.x >> 6, lane = threadIdx.x & 63;
  constexpr int RPL = IN / 64;
  for (int ii = 0; ii < OPW; ++ii) {
    int o = (oc * 4 + w) * OPW + ii;
    const float* wr = W + (size_t)o * IN;
    float acc = 0.f;
    #pragma unroll
    for (int r = 0; r < RPL; ++r) acc += wr[r * 64 + lane] * sIn[r * 64 + lane];
    #pragma unroll
    for (int m = 32; m >= 1; m >>= 1) acc += __shfl_xor(acc, m);
    if (lane == 0) {
      acc += lb[o];
      if (BNRELU) {
        float s = g[o] * (1.0f / sqrtf(1.0f + EPSF));
        acc = fmaxf(acc * s + bbias[o], 0.0f);
      }
      out[(size_t)b * OUT + o] = acc;
    }
  }
}

extern "C" void kernel_launch(void* const* d_in, const int* in_sizes, int n_in,
                              void* d_out, int out_size, void* d_ws, size_t ws_size,
                              hipStream_t stream) {
  const float* x   = (const float*)d_in[0];
  const float* w1  = (const float*)d_in[1];
  const float* g1  = (const float*)d_in[2];
  const float* b1  = (const float*)d_in[3];
  const float* w2  = (const float*)d_in[4];
  const float* g2  = (const float*)d_in[5];
  const float* b2  = (const float*)d_in[6];
  const float* w3  = (const float*)d_in[7];
  const float* g3  = (const float*)d_in[8];
  const float* b3  = (const float*)d_in[9];
  const float* w4  = (const float*)d_in[10];
  const float* g4  = (const float*)d_in[11];
  const float* b4  = (const float*)d_in[12];
  const float* lw1 = (const float*)d_in[13];
  const float* lb1 = (const float*)d_in[14];
  const float* g5  = (const float*)d_in[15];
  const float* b5  = (const float*)d_in[16];
  const float* lw2 = (const float*)d_in[17];
  const float* lb2 = (const float*)d_in[18];
  const float* g6  = (const float*)d_in[19];
  const float* b6  = (const float*)d_in[20];
  const float* lw3 = (const float*)d_in[21];
  const float* lb3 = (const float*)d_in[22];
  float* out = (float*)d_out;

  char* ws = (char*)d_ws;
  size_t off = 0;
  auto alloc = [&](size_t bytes) -> char* {
    char* p = ws + off;
    off += (bytes + 255) & ~255ULL;
    return p;
  };
  int*   idx    = (int*)  alloc((size_t)BB * NN * KK * 4);
  float* xx     = (float*)alloc((size_t)BB * NN * 4);
  float* xT0    = (float*)alloc((size_t)BB * 3 * NN * 4);
  float* bufA   = (float*)alloc((size_t)BB * NN * 64 * 4);
  float* bufB   = (float*)alloc((size_t)BB * NN * 64 * 4);
  float* pooled = (float*)alloc((size_t)BB * 320 * 4);
  float* h1     = (float*)alloc((size_t)BB * 1024 * 4);
  float* h2     = (float*)alloc((size_t)BB * 512 * 4);
  float* uc     = (float*)alloc((size_t)BB * NN * 256 * 4);
  ushort* xhl   = (ushort*)alloc((size_t)BB * NN * 128 * 2);

  size_t dbytes_per_b = (size_t)NN * NN * 4;
  size_t rem = (ws_size > off) ? (ws_size - off) : 0;
  int gmax = (int)(rem / dbytes_per_b);
  if (gmax > 32) gmax = 32;
  int gp2 = 1;
  while (gp2 * 2 <= gmax) gp2 <<= 1;
  gmax = gp2 < 1 ? 1 : gp2;
  u32* Dm = (u32*)alloc((size_t)gmax * dbytes_per_b);

  int gshift = -1;
  if (gmax >= 8) {
    int gper = gmax >> 3;
    gshift = 0;
    while ((1 << gshift) < gper) ++gshift;
  }

  dim3 blk(256);
  int bn_blocks = (BB * NN + 255) / 256;

  // per layer: [dist + ucGEMM merged] -> topk -> gmp
  auto layer64 = [&](const float* feat, const float* w, const float* gg, const float* bbv,
                     float* yout, int ooff, bool next) {
    for (int b0 = 0; b0 < BB; b0 += gmax) {
      int distBlocks = gmax * 64;
      int ucBlocks = (b0 == 0) ? 2048 : 0;
      ducp_kernel<64><<<distBlocks + ucBlocks, blk, 0, stream>>>(
          xhl, xx, Dm, b0, gshift, distBlocks, feat, w, uc);
      topk_kernel<<<(gmax * NN) / 4, blk, 0, stream>>>(Dm, idx, b0);
    }
    if (next)
      gmp_kernel<64, true><<<(BB * NN * 16) / 256, blk, 0, stream>>>(
          uc, idx, gg, bbv, yout, (u32*)pooled, ooff, xhl, xx);
    else
      gmp_kernel<64, false><<<(BB * NN * 16) / 256, blk, 0, stream>>>(
          uc, idx, gg, bbv, yout, (u32*)pooled, ooff, nullptr, nullptr);
  };

  // ---- layer 1 (C=3 -> 64) ----
  t3xx_kernel<<<bn_blocks, blk, 0, stream>>>(x, xT0, xx, pooled);
  tu3_kernel<<<8192 + 16384, blk, 0, stream>>>(x, xT0, xx, idx, w1, uc);
  gmp_kernel<64, true><<<(BB * NN * 16) / 256, blk, 0, stream>>>(
      uc, idx, g1, b1, bufA, (u32*)pooled, 0, xhl, xx);

  // ---- layer 2 (64 -> 64) ----
  layer64(bufA, w2, g2, b2, bufB, 64, true);

  // ---- layer 3 (64 -> 64) ----
  layer64(bufB, w3, g3, b3, bufA, 128, true);

  // ---- layer 4 (64 -> 128) ----
  for (int b0 = 0; b0 < BB; b0 += gmax) {
    int distBlocks = gmax * 64;
    int ucBlocks = (b0 == 0) ? 2048 : 0;
    ducp_kernel<128><<<distBlocks + ucBlocks, blk, 0, stream>>>(
        xhl, xx, Dm, b0, gshift, distBlocks, bufA, w4, uc);
    topk_kernel<<<(gmax * NN) / 4, blk, 0, stream>>>(Dm, idx, b0);
  }
  gmp_kernel<128, false><<<(BB * NN * 32) / 256, blk, 0, stream>>>(
      uc, idx, g4, b4, bufB, (u32*)pooled, 192, nullptr, nullptr);

  // ---- classifier ----
  fcw_kernel<320, 1024, 32, true><<<dim3(BB, 8), blk, 0, stream>>>(pooled, lw1, lb1, g5, b5, h1);
  fcw_kernel<1024, 512, 16, true><<<dim3(BB, 8), blk, 0, stream>>>(h1, lw2, lb2, g6, b6, h2);
  fcw_kernel<512, 40, 10, false><<<dim3(BB, 1), blk, 0, stream>>>(h2, lw3, lb3, nullptr, nullptr, out);
}

// Round 19
// 414.218 us; speedup vs baseline: 1.5801x; 1.0247x over previous
//
#include <hip/hip_runtime.h>
#include <math.h>

#define BB 32
#define NN 1024
#define KK 20
typedef unsigned long long u64;
typedef unsigned int u32;
typedef unsigned short ushort;
static constexpr float EPSF = 1e-5f;

typedef __attribute__((ext_vector_type(8))) short bf16x8;
typedef __attribute__((ext_vector_type(4))) float f32x4;

// ---------------- fused transpose (B,N,3)->(B,3,N) + xx + pooled zero ----------------
__global__ void t3xx_kernel(const float* __restrict__ x, float* __restrict__ xT,
                            float* __restrict__ xx, float* __restrict__ pooled) {
  int t = blockIdx.x * blockDim.x + threadIdx.x;
  if (t >= BB * NN) return;
  if (t < BB * 320) pooled[t] = 0.0f;
  int b = t >> 10, i = t & (NN - 1);
  float v0 = x[(size_t)t * 3 + 0], v1 = x[(size_t)t * 3 + 1], v2 = x[(size_t)t * 3 + 2];
  xT[((size_t)b * 3 + 0) * NN + i] = v0;
  xT[((size_t)b * 3 + 1) * NN + i] = v1;
  xT[((size_t)b * 3 + 2) * NN + i] = v2;
  float s = 0.f;
  s += v0 * v0; s += v1 * v1; s += v2 * v2;
  xx[t] = s;
}

// ---------------- monotone f32 -> u32 order map ----------------
__device__ __forceinline__ u32 map_m(float d) {
  u32 bits = __float_as_uint(d);
  return bits ^ (u32)(((int)bits >> 31) | 0x80000000);
}

__device__ __forceinline__ double shflxd(double v, int m) {
  long long u = __double_as_longlong(v);
  int lo = (int)(u & 0xFFFFFFFFll);
  int hi = (int)(((u64)u) >> 32);
  lo = __shfl_xor(lo, m);
  hi = __shfl_xor(hi, m);
  return __longlong_as_double(((long long)hi << 32) | (u32)lo);
}

// descending bitonic sorts
__device__ __forceinline__ u32 lane_sort64_u32(u32 v, int lane) {
  #pragma unroll
  for (int kk = 2; kk <= 64; kk <<= 1)
    #pragma unroll
    for (int j = kk >> 1; j > 0; j >>= 1) {
      u32 pv = (u32)__shfl_xor((int)v, j);
      bool keepMax = (((lane & j) == 0) == ((lane & kk) == 0));
      u32 mx = v > pv ? v : pv, mn = v > pv ? pv : v;
      v = keepMax ? mx : mn;
    }
  return v;
}

__device__ __forceinline__ double lane_sort64(double v, int lane) {
  #pragma unroll
  for (int kk = 2; kk <= 64; kk <<= 1)
    #pragma unroll
    for (int j = kk >> 1; j > 0; j >>= 1) {
      double pv = shflxd(v, j);
      bool keepMax = (((lane & j) == 0) == ((lane & kk) == 0));
      v = keepMax ? fmax(v, pv) : fmin(v, pv);
    }
  return v;
}

__device__ __forceinline__ double lane_sort32(double v, int lane) {
  #pragma unroll
  for (int kk = 2; kk <= 32; kk <<= 1)
    #pragma unroll
    for (int j = kk >> 1; j > 0; j >>= 1) {
      double pv = shflxd(v, j);
      bool keepMax = (((lane & j) == 0) == ((lane & kk) == 0));
      v = keepMax ? fmax(v, pv) : fmin(v, pv);
    }
  return v;
}

__device__ __forceinline__ void key_decode_write(double res, int lane, int* __restrict__ orow) {
  if (lane < KK) {
    double md = trunc(res * (1.0 / 1024.0));
    double rd = fma(md, -1024.0, res);
    orow[lane] = 1023 - (int)rd;
  }
}

// u32 first-stage filter + f64 survivor sort (exact). m[e], e=(q<<2)|c: j = q*256+lane*4+c
__device__ __forceinline__ void topk_sel(u32 (&m)[16], int lane,
                                         volatile double* __restrict__ sb,
                                         int* __restrict__ orow) {
  u32 h = m[0];
  #pragma unroll
  for (int e = 1; e < 16; ++e) h = m[e] > h ? m[e] : h;
  u32 sh = lane_sort64_u32(h, lane);
  u32 T = (u32)__shfl((int)sh, KK - 1);

  int cnt = 0;
  #pragma unroll
  for (int e = 0; e < 16; ++e) cnt += (m[e] >= T) ? 1 : 0;
  int scan = cnt;
  #pragma unroll
  for (int d = 1; d < 64; d <<= 1) {
    int nv = __shfl_up(scan, d);
    if (lane >= d) scan += nv;
  }
  int total = __shfl(scan, 63);
  double based = (double)(1023 - lane * 4);

  if (total <= 64) {
    int ofs = scan - cnt;
    sb[lane] = 0.0;
    #pragma unroll
    for (int e = 0; e < 16; ++e)
      if (m[e] >= T) {
        double kd = fma((double)m[e], 1024.0, based - (double)((e >> 2) * 256 + (e & 3)));
        sb[ofs++] = kd;
      }
    double v = sb[lane];
    v = (total <= 32) ? lane_sort32(v, lane) : lane_sort64(v, lane);
    key_decode_write(v, lane, orow);
  } else {
    // exact fallback (tie-heavy rows): f64-key tournament
    double k[16];
    #pragma unroll
    for (int e = 0; e < 16; ++e)
      k[e] = fma((double)m[e], 1024.0, based - (double)((e >> 2) * 256 + (e & 3)));
    double lm = k[0];
    #pragma unroll
    for (int e = 1; e < 16; ++e) lm = fmax(lm, k[e]);
    double res = 0.0;
    for (int t = 0; t < KK; ++t) {
      double w = lm;
      #pragma unroll
      for (int mm = 1; mm < 64; mm <<= 1) w = fmax(w, shflxd(w, mm));
      if (lane == t) res = w;
      bool win = (lm == w);
      #pragma unroll
      for (int e = 0; e < 16; ++e) k[e] = (k[e] == w) ? 0.0 : k[e];
      if (win) {
        double n0 = fmax(k[0], k[1]);
        #pragma unroll
        for (int e = 2; e < 16; ++e) n0 = fmax(n0, k[e]);
        lm = n0;
      }
    }
    key_decode_write(res, lane, orow);
  }
}

// ---------------- merged: MFMA dist (u32-m output, XCD-swizzled) + uc GEMM ----------------
// dist output path: operand-swapped MFMA so each lane packs 4 consecutive-j values -> uint4 stores.
#define CC 64
template<int O>
__global__ __launch_bounds__(256) void ducp_kernel(
    const ushort* __restrict__ xhl,  // (B,N,128) [hi|lo]
    const float* __restrict__ xx,    // (B,N)
    u32* __restrict__ Dm,            // (g,N,N) mapped u32
    int b0, int gshift, int distBlocks,
    const float* __restrict__ xfeat, // (B,N,64)
    const float* __restrict__ w,     // (O,128)
    float* __restrict__ uc) {        // (B,N,2O)
  __shared__ float4 Ws[O * 16];
  __shared__ float4 As[32 * 16];

  if ((int)blockIdx.x < distBlocks) {
    // ----- distance part -----
    int bid = blockIdx.x;
    int b, tile;
    if (gshift >= 0) {
      int xcd = bid & 7;
      int rest = bid >> 3;
      int bl = rest & ((1 << gshift) - 1);
      tile = rest >> gshift;
      b = b0 + xcd + (bl << 3);
    } else {
      b = b0 + (bid >> 6);
      tile = bid & 63;
    }
    int dloc = b - b0;
    int wv = threadIdx.x >> 6;
    int lane = threadIdx.x & 63;
    int wm = wv >> 1, wn = wv & 1;
    int i0 = (tile >> 3) * 128 + wm * 64;
    int j0 = (tile & 7) * 128 + wn * 64;
    int r16 = lane & 15;
    int kg = lane >> 4;

    const ushort* base = xhl + (size_t)b * NN * 128;
    f32x4 acc[4][4];   // acc[tj][ti]: j = j0+tj*16+kg*4+r, i = i0+ti*16+r16
    #pragma unroll
    for (int tj = 0; tj < 4; ++tj)
      #pragma unroll
      for (int ti = 0; ti < 4; ++ti) acc[tj][ti] = (f32x4){0.f, 0.f, 0.f, 0.f};

    #pragma unroll
    for (int ks = 0; ks < 2; ++ks) {
      int k0 = ks * 32 + kg * 8;
      bf16x8 ah[4], al[4], bh[4], bl[4];
      // A-frags from j-rows (output rows = j)
      #pragma unroll
      for (int tj = 0; tj < 4; ++tj) {
        const ushort* pr = base + (size_t)(j0 + tj * 16 + r16) * 128 + k0;
        ah[tj] = *(const bf16x8*)pr;
        al[tj] = *(const bf16x8*)(pr + 64);
      }
      // B-frags from i-rows (output cols = i)
      #pragma unroll
      for (int ti = 0; ti < 4; ++ti) {
        const ushort* pr = base + (size_t)(i0 + ti * 16 + r16) * 128 + k0;
        bh[ti] = *(const bf16x8*)pr;
        bl[ti] = *(const bf16x8*)(pr + 64);
      }
      #pragma unroll
      for (int tj = 0; tj < 4; ++tj)
        #pragma unroll
        for (int ti = 0; ti < 4; ++ti) {
          acc[tj][ti] = __builtin_amdgcn_mfma_f32_16x16x32_bf16(ah[tj], bh[ti], acc[tj][ti], 0, 0, 0);
          acc[tj][ti] = __builtin_amdgcn_mfma_f32_16x16x32_bf16(ah[tj], bl[ti], acc[tj][ti], 0, 0, 0);
          acc[tj][ti] = __builtin_amdgcn_mfma_f32_16x16x32_bf16(al[tj], bh[ti], acc[tj][ti], 0, 0, 0);
          acc[tj][ti] = __builtin_amdgcn_mfma_f32_16x16x32_bf16(al[tj], bl[ti], acc[tj][ti], 0, 0, 0);
        }
    }

    const float* xxb = xx + (size_t)b * NN;
    u32* Dg = Dm + (size_t)dloc * NN * NN;
    #pragma unroll
    for (int tj = 0; tj < 4; ++tj) {
      // xx_j for the 4 consecutive j this lane packs
      float4 xjv = *(const float4*)(xxb + j0 + tj * 16 + kg * 4);
      #pragma unroll
      for (int ti = 0; ti < 4; ++ti) {
        int irow = i0 + ti * 16 + r16;
        uint4 o;
        o.x = map_m(2.f * acc[tj][ti][0] - xjv.x);
        o.y = map_m(2.f * acc[tj][ti][1] - xjv.y);
        o.z = map_m(2.f * acc[tj][ti][2] - xjv.z);
        o.w = map_m(2.f * acc[tj][ti][3] - xjv.w);
        *(uint4*)(Dg + (size_t)irow * NN + j0 + tj * 16 + kg * 4) = o;
      }
    }
  } else {
    // ----- uc GEMM part (LDS staging; proven) -----
    int id = blockIdx.x - distBlocks;
    int part = id >> 10;
    int tile = id & 1023;
    int b = tile >> 5;
    int i0 = (tile & 31) * 32;

    const float4* w4 = (const float4*)w;
    for (int r = threadIdx.x; r < O * 16; r += 256) {
      int rowc = r >> 4, c4 = r & 15;
      float4 v;
      if (part == 0) {
        v = w4[(size_t)rowc * 32 + c4];
      } else {
        float4 lo = w4[(size_t)rowc * 32 + c4];
        float4 hi = w4[(size_t)rowc * 32 + 16 + c4];
        v = make_float4(hi.x - lo.x, hi.y - lo.y, hi.z - lo.z, hi.w - lo.w);
      }
      Ws[(rowc << 4) + (c4 ^ (rowc & 7))] = v;
    }
    const float4* xa = (const float4*)(xfeat + ((size_t)b * NN + i0) * CC);
    for (int r = threadIdx.x; r < 32 * 16; r += 256) As[r] = xa[r];
    __syncthreads();

    int col = threadIdx.x % O;
    int pg = threadIdx.x / O;
    constexpr int PPT = 32 * O / 256;
    float4 wc[16];
    #pragma unroll
    for (int c4 = 0; c4 < 16; ++c4) wc[c4] = Ws[(col << 4) + (c4 ^ (col & 7))];

    #pragma unroll
    for (int pp = 0; pp < PPT; ++pp) {
      int p = pg * PPT + pp;
      float acc = 0.f;
      #pragma unroll
      for (int c4 = 0; c4 < 16; ++c4) {
        float4 a = As[(p << 4) + c4];
        acc += a.x * wc[c4].x; acc += a.y * wc[c4].y;
        acc += a.z * wc[c4].z; acc += a.w * wc[c4].w;
      }
      uc[((size_t)b * NN + i0 + p) * (2 * O) + part * O + col] = acc;
    }
  }
}

// ---------------- wave-per-row top-20 over u32 m ----------------
__global__ __launch_bounds__(256) void topk_kernel(
    const u32* __restrict__ Dm, int* __restrict__ oidx, int b0) {
  __shared__ double sb[4][64];
  int wslot = threadIdx.x >> 6;
  int wid = (blockIdx.x << 2) + wslot;
  int lane = threadIdx.x & 63;
  int row = wid & (NN - 1);
  int bg = wid >> 10;

  const uint4* dp = (const uint4*)(Dm + ((size_t)bg * NN + row) * NN);
  u32 m[16];
  #pragma unroll
  for (int q = 0; q < 4; ++q) {
    uint4 v = dp[q * 64 + lane];
    m[q * 4 + 0] = v.x; m[q * 4 + 1] = v.y; m[q * 4 + 2] = v.z; m[q * 4 + 3] = v.w;
  }
  topk_sel(m, lane, &sb[wslot][0], oidx + ((size_t)(b0 + bg) * NN + row) * KK);
}

// ---------------- merged layer-1: fused C=3 dist+top-20 (blocks < 8192) + uc3 ----------------
__global__ __launch_bounds__(256) void tu3_kernel(
    const float* __restrict__ x,   // (B,N,3)
    const float* __restrict__ xT,  // (B,3,N)
    const float* __restrict__ xx,  // (B,N)
    int* __restrict__ oidx,
    const float* __restrict__ w1,
    float* __restrict__ uc) {
  __shared__ double sb[4][64];
  if ((int)blockIdx.x < 8192) {
    int wslot = threadIdx.x >> 6;
    int wid = ((int)blockIdx.x << 2) + wslot;
    int lane = threadIdx.x & 63;
    int row = wid & (NN - 1);
    int b = wid >> 10;

    const float* xr = x + ((size_t)b * NN + row) * 3;
    float x0 = xr[0], x1 = xr[1], x2 = xr[2];
    const float* xTb = xT + (size_t)b * 3 * NN;
    const float* xxb = xx + (size_t)b * NN;

    u32 m[16];
    #pragma unroll
    for (int q = 0; q < 4; ++q) {
      int f4i = q * 64 + lane;
      float4 a  = ((const float4*)xTb)[f4i];
      float4 bv = ((const float4*)(xTb + NN))[f4i];
      float4 c  = ((const float4*)(xTb + 2 * NN))[f4i];
      float4 xj = ((const float4*)xxb)[f4i];
      float d0 = 0.f; d0 += x0 * a.x; d0 += x1 * bv.x; d0 += x2 * c.x;
      float d1 = 0.f; d1 += x0 * a.y; d1 += x1 * bv.y; d1 += x2 * c.y;
      float d2 = 0.f; d2 += x0 * a.z; d2 += x1 * bv.z; d2 += x2 * c.z;
      float d3 = 0.f; d3 += x0 * a.w; d3 += x1 * bv.w; d3 += x2 * c.w;
      m[q * 4 + 0] = map_m(2.f * d0 - xj.x);
      m[q * 4 + 1] = map_m(2.f * d1 - xj.y);
      m[q * 4 + 2] = map_m(2.f * d2 - xj.z);
      m[q * 4 + 3] = map_m(2.f * d3 - xj.w);
    }
    topk_sel(m, lane, &sb[wslot][0], oidx + ((size_t)b * NN + row) * KK);
  } else {
    int t = ((int)blockIdx.x - 8192) * 256 + threadIdx.x;   // B*N*128
    int col = t & 127;
    int i = (t >> 7) & (NN - 1);
    int b = t >> 17;
    const float* xr = x + ((size_t)b * NN + i) * 3;
    float x0 = xr[0], x1 = xr[1], x2 = xr[2];
    float r;
    if (col < 64) {
      const float* wr = w1 + col * 6;
      r = wr[0] * x0 + wr[1] * x1 + wr[2] * x2;
    } else {
      const float* wr = w1 + (col - 64) * 6;
      r = (wr[3] - wr[0]) * x0 + (wr[4] - wr[1]) * x1 + (wr[5] - wr[2]) * x2;
    }
    uc[(size_t)t] = r;
  }
}

// ---- gather-max + BN/ReLU + global-pool + (NEXT) y/xhl/xx prep. XCD-swizzled blocks. ----
template<int O, bool NEXT>
__global__ __launch_bounds__(256) void gmp_kernel(
    const float* __restrict__ uc,   // (B,N,2O)
    const int*   __restrict__ idx,  // (B,N,K)
    const float* __restrict__ g,
    const float* __restrict__ bb,
    float* __restrict__ y,          // (B,N,O)
    u32* __restrict__ pooled,       // (B,320) u32 bit patterns (all >= 0)
    int ooff,
    ushort* __restrict__ xhl,       // (B,N,128) [hi|lo]   (NEXT only)
    float* __restrict__ xx) {       // (B,N)               (NEXT only)
  constexpr int O4 = O / 4;
  constexpr int PPB = 256 / O4;
  int bid = blockIdx.x;
  int xcd = bid & 7;
  int rest = bid >> 3;
  int bgrp = rest & 3;
  int jblk = rest >> 2;
  int b = xcd + (bgrp << 3);
  int o4 = threadIdx.x & (O4 - 1);
  int i = jblk * PPB + (threadIdx.x >> (O == 64 ? 4 : 5));

  const int* irow = idx + ((size_t)b * NN + i) * KK;
  int jj[KK];
  #pragma unroll
  for (int k = 0; k < KK; ++k) jj[k] = irow[k];

  const float* ucb = uc + (size_t)b * NN * (2 * O);
  float4 vm = make_float4(-INFINITY, -INFINITY, -INFINITY, -INFINITY);
  #pragma unroll
  for (int k = 0; k < KK; ++k) {
    float4 v = *(const float4*)(ucb + (size_t)jj[k] * (2 * O) + o4 * 4);
    vm.x = fmaxf(vm.x, v.x); vm.y = fmaxf(vm.y, v.y);
    vm.z = fmaxf(vm.z, v.z); vm.w = fmaxf(vm.w, v.w);
  }
  float4 c0 = *(const float4*)(ucb + (size_t)i * (2 * O) + O + o4 * 4);
  float4 gv = ((const float4*)g)[o4];
  float4 bv = ((const float4*)bb)[o4];
  const float inv = 1.0f / sqrtf(1.0f + EPSF);
  float4 o;
  o.x = fmaxf((gv.x * inv) * (vm.x + c0.x) + bv.x, 0.f);
  o.y = fmaxf((gv.y * inv) * (vm.y + c0.y) + bv.y, 0.f);
  o.z = fmaxf((gv.z * inv) * (vm.z + c0.z) + bv.z, 0.f);
  o.w = fmaxf((gv.w * inv) * (vm.w + c0.w) + bv.w, 0.f);

  if constexpr (NEXT) {
    *(float4*)(y + ((size_t)b * NN + i) * O + o4 * 4) = o;
    ushort4 hi, lo;
    u32 q0 = __float_as_uint(o.x); hi.x = q0 >> 16;
    u32 q1 = __float_as_uint(o.y); hi.y = q1 >> 16;
    u32 q2 = __float_as_uint(o.z); hi.z = q2 >> 16;
    u32 q3 = __float_as_uint(o.w); hi.w = q3 >> 16;
    lo.x = __float_as_uint(o.x - __uint_as_float(q0 & 0xFFFF0000u)) >> 16;
    lo.y = __float_as_uint(o.y - __uint_as_float(q1 & 0xFFFF0000u)) >> 16;
    lo.z = __float_as_uint(o.z - __uint_as_float(q2 & 0xFFFF0000u)) >> 16;
    lo.w = __float_as_uint(o.w - __uint_as_float(q3 & 0xFFFF0000u)) >> 16;
    ushort* xr = xhl + ((size_t)b * NN + i) * 128;
    *(ushort4*)(xr + o4 * 4) = hi;
    *(ushort4*)(xr + 64 + o4 * 4) = lo;
    float px = o.x * o.x + o.y * o.y + o.z * o.z + o.w * o.w;
    px += __shfl_xor(px, 1);
    px += __shfl_xor(px, 2);
    px += __shfl_xor(px, 4);
    px += __shfl_xor(px, 8);
    if (o4 == 0) xx[(size_t)b * NN + i] = px;
  }

  __shared__ float4 sm[256];
  sm[threadIdx.x] = o;
  __syncthreads();
  if (threadIdx.x < O4) {
    float4 m = sm[threadIdx.x];
    #pragma unroll
    for (int r = 1; r < PPB; ++r) {
      float4 v = sm[threadIdx.x + r * O4];
      m.x = fmaxf(m.x, v.x); m.y = fmaxf(m.y, v.y);
      m.z = fmaxf(m.z, v.z); m.w = fmaxf(m.w, v.w);
    }
    u32* dst = pooled + (size_t)b * 320 + ooff + threadIdx.x * 4;
    atomicMax(dst + 0, __float_as_uint(m.x));
    atomicMax(dst + 1, __float_as_uint(m.y));
    atomicMax(dst + 2, __float_as_uint(m.z));
    atomicMax(dst + 3, __float_as_uint(m.w));
  }
}

// ---------------- coalesced fc: wave-per-output, LDS-staged input ----------------
template<int IN, int OUT, int OPW, bool BNRELU>
__global__ __launch_bounds__(256) void fcw_kernel(
    const float* __restrict__ in, const float* __restrict__ W,
    const float* __restrict__ lb, const float* __restrict__ g,
    const float* __restrict__ bbias, float* __restrict__ out) {
  int b = blockIdx.x;
  int oc = blockIdx.y;
  __shared__ float sIn[IN];
  for (int r = threadIdx.x; r < IN; r += 256) sIn[r] = in[(size_t)b * IN + r];
  __syncthreads();
  int w = threadIdx.x >> 6, lane = threadIdx.x & 63;
  constexpr int RPL = IN / 64;
  for (int ii = 0; ii < OPW; ++ii) {
    int o = (oc * 4 + w) * OPW + ii;
    const float* wr = W + (size_t)o * IN;
    float acc = 0.f;
    #pragma unroll
    for (int r = 0; r < RPL; ++r) acc += wr[r * 64 + lane] * sIn[r * 64 + lane];
    #pragma unroll
    for (int m = 32; m >= 1; m >>= 1) acc += __shfl_xor(acc, m);
    if (lane == 0) {
      acc += lb[o];
      if (BNRELU) {
        float s = g[o] * (1.0f / sqrtf(1.0f + EPSF));
        acc = fmaxf(acc * s + bbias[o], 0.0f);
      }
      out[(size_t)b * OUT + o] = acc;
    }
  }
}

extern "C" void kernel_launch(void* const* d_in, const int* in_sizes, int n_in,
                              void* d_out, int out_size, void* d_ws, size_t ws_size,
                              hipStream_t stream) {
  const float* x   = (const float*)d_in[0];
  const float* w1  = (const float*)d_in[1];
  const float* g1  = (const float*)d_in[2];
  const float* b1  = (const float*)d_in[3];
  const float* w2  = (const float*)d_in[4];
  const float* g2  = (const float*)d_in[5];
  const float* b2  = (const float*)d_in[6];
  const float* w3  = (const float*)d_in[7];
  const float* g3  = (const float*)d_in[8];
  const float* b3  = (const float*)d_in[9];
  const float* w4  = (const float*)d_in[10];
  const float* g4  = (const float*)d_in[11];
  const float* b4  = (const float*)d_in[12];
  const float* lw1 = (const float*)d_in[13];
  const float* lb1 = (const float*)d_in[14];
  const float* g5  = (const float*)d_in[15];
  const float* b5  = (const float*)d_in[16];
  const float* lw2 = (const float*)d_in[17];
  const float* lb2 = (const float*)d_in[18];
  const float* g6  = (const float*)d_in[19];
  const float* b6  = (const float*)d_in[20];
  const float* lw3 = (const float*)d_in[21];
  const float* lb3 = (const float*)d_in[22];
  float* out = (float*)d_out;

  char* ws = (char*)d_ws;
  size_t off = 0;
  auto alloc = [&](size_t bytes) -> char* {
    char* p = ws + off;
    off += (bytes + 255) & ~255ULL;
    return p;
  };
  int*   idx    = (int*)  alloc((size_t)BB * NN * KK * 4);
  float* xx     = (float*)alloc((size_t)BB * NN * 4);
  float* xT0    = (float*)alloc((size_t)BB * 3 * NN * 4);
  float* bufA   = (float*)alloc((size_t)BB * NN * 64 * 4);
  float* bufB   = (float*)alloc((size_t)BB * NN * 64 * 4);
  float* pooled = (float*)alloc((size_t)BB * 320 * 4);
  float* h1     = (float*)alloc((size_t)BB * 1024 * 4);
  float* h2     = (float*)alloc((size_t)BB * 512 * 4);
  float* uc     = (float*)alloc((size_t)BB * NN * 256 * 4);
  ushort* xhl   = (ushort*)alloc((size_t)BB * NN * 128 * 2);

  size_t dbytes_per_b = (size_t)NN * NN * 4;
  size_t rem = (ws_size > off) ? (ws_size - off) : 0;
  int gmax = (int)(rem / dbytes_per_b);
  if (gmax > 32) gmax = 32;
  int gp2 = 1;
  while (gp2 * 2 <= gmax) gp2 <<= 1;
  gmax = gp2 < 1 ? 1 : gp2;
  u32* Dm = (u32*)alloc((size_t)gmax * dbytes_per_b);

  int gshift = -1;
  if (gmax >= 8) {
    int gper = gmax >> 3;
    gshift = 0;
    while ((1 << gshift) < gper) ++gshift;
  }

  dim3 blk(256);
  int bn_blocks = (BB * NN + 255) / 256;

  // per layer: [dist + ucGEMM merged] -> topk -> gmp
  auto layer64 = [&](const float* feat, const float* w, const float* gg, const float* bbv,
                     float* yout, int ooff, bool next) {
    for (int b0 = 0; b0 < BB; b0 += gmax) {
      int distBlocks = gmax * 64;
      int ucBlocks = (b0 == 0) ? 2048 : 0;
      ducp_kernel<64><<<distBlocks + ucBlocks, blk, 0, stream>>>(
          xhl, xx, Dm, b0, gshift, distBlocks, feat, w, uc);
      topk_kernel<<<(gmax * NN) / 4, blk, 0, stream>>>(Dm, idx, b0);
    }
    if (next)
      gmp_kernel<64, true><<<(BB * NN * 16) / 256, blk, 0, stream>>>(
          uc, idx, gg, bbv, yout, (u32*)pooled, ooff, xhl, xx);
    else
      gmp_kernel<64, false><<<(BB * NN * 16) / 256, blk, 0, stream>>>(
          uc, idx, gg, bbv, yout, (u32*)pooled, ooff, nullptr, nullptr);
  };

  // ---- layer 1 (C=3 -> 64) ----
  t3xx_kernel<<<bn_blocks, blk, 0, stream>>>(x, xT0, xx, pooled);
  tu3_kernel<<<8192 + 16384, blk, 0, stream>>>(x, xT0, xx, idx, w1, uc);
  gmp_kernel<64, true><<<(BB * NN * 16) / 256, blk, 0, stream>>>(
      uc, idx, g1, b1, bufA, (u32*)pooled, 0, xhl, xx);

  // ---- layer 2 (64 -> 64) ----
  layer64(bufA, w2, g2, b2, bufB, 64, true);

  // ---- layer 3 (64 -> 64) ----
  layer64(bufB, w3, g3, b3, bufA, 128, true);

  // ---- layer 4 (64 -> 128) ----
  for (int b0 = 0; b0 < BB; b0 += gmax) {
    int distBlocks = gmax * 64;
    int ucBlocks = (b0 == 0) ? 2048 : 0;
    ducp_kernel<128><<<distBlocks + ucBlocks, blk, 0, stream>>>(
        xhl, xx, Dm, b0, gshift, distBlocks, bufA, w4, uc);
    topk_kernel<<<(gmax * NN) / 4, blk, 0, stream>>>(Dm, idx, b0);
  }
  gmp_kernel<128, false><<<(BB * NN * 32) / 256, blk, 0, stream>>>(
      uc, idx, g4, b4, bufB, (u32*)pooled, 192, nullptr, nullptr);

  // ---- classifier ----
  fcw_kernel<320, 1024, 32, true><<<dim3(BB, 8), blk, 0, stream>>>(pooled, lw1, lb1, g5, b5, h1);
  fcw_kernel<1024, 512, 16, true><<<dim3(BB, 8), blk, 0, stream>>>(h1, lw2, lb2, g6, b6, h2);
  fcw_kernel<512, 40, 10, false><<<dim3(BB, 1), blk, 0, stream>>>(h2, lw3, lb3, nullptr, nullptr, out);
}